// Round 1
// baseline (146.079 us; speedup 1.0000x reference)
//
#include <hip/hip_runtime.h>
#include <hip/hip_bf16.h>
#include <cstdint>
#include <cstddef>

#define NNODES 4096
#define NHEADS 4
#define NBR_STRIDE 128

// ---------------------------------------------------------------------------
// Kernel 1: build neighbor lists (deterministic wave-ballot compaction).
// One wave per row; scans 4096 columns in 64-lane chunks, compacts indices
// of adj>0 in column order via ballot + prefix popcount.
// ---------------------------------------------------------------------------
__global__ __launch_bounds__(256) void build_nbr_kernel(
    const float* __restrict__ adj, int* __restrict__ nbr, int* __restrict__ deg) {
    int wave = threadIdx.x >> 6;
    int lane = threadIdx.x & 63;
    int row = blockIdx.x * 4 + wave;
    if (row >= NNODES) return;
    const float* arow = adj + (size_t)row * NNODES;
    int base = 0;
    for (int c = 0; c < NNODES; c += 64) {
        float v = arow[c + lane];
        bool nz = v > 0.0f;
        unsigned long long m = __ballot(nz);
        if (nz) {
            int pos = base + __popcll(m & ((1ull << lane) - 1ull));
            if (pos < NBR_STRIDE) nbr[row * NBR_STRIDE + pos] = c + lane;
        }
        base += __popcll(m);
    }
    if (lane == 0) deg[row] = base < NBR_STRIDE ? base : NBR_STRIDE;
}

// ---------------------------------------------------------------------------
// Kernel 2: pack W[h][f][o] -> Wp[f][h*FO+o] (row-major K x (4*FO))
// ---------------------------------------------------------------------------
__global__ __launch_bounds__(256) void pack_w_kernel(
    const float* __restrict__ W, float* __restrict__ Wp, int K, int FO) {
    int idx = blockIdx.x * blockDim.x + threadIdx.x;
    int ncols = NHEADS * FO;
    if (idx >= K * ncols) return;
    int f = idx / ncols;
    int c = idx - f * ncols;
    int h = c / FO;
    int o = c - h * FO;
    Wp[idx] = W[((size_t)h * K + f) * FO + o];
}

// ---------------------------------------------------------------------------
// Kernel 3: f32 tiled GEMM  C[M,N] = A[M,K] * B[K,N]   (row-major all)
// BM=BN=64, BK=32, 256 threads, 4x4 per thread.
// ---------------------------------------------------------------------------
__global__ __launch_bounds__(256) void gemm_f32_kernel(
    const float* __restrict__ A, const float* __restrict__ B,
    float* __restrict__ C, int M, int N, int K) {
    constexpr int BM = 64, BN = 64, BK = 32;
    __shared__ float As[BM][BK + 4];
    __shared__ float Bs[BK][BN + 4];
    int tid = threadIdx.x;
    int tx = tid & 15, ty = tid >> 4;
    int rowBase = blockIdx.x * BM;
    int colBase = blockIdx.y * BN;
    float acc[4][4] = {};
    for (int k0 = 0; k0 < K; k0 += BK) {
        // Load A tile: 64x32 = 512 float4, 2 per thread
        #pragma unroll
        for (int i = 0; i < 2; ++i) {
            int q = tid + i * 256;
            int r = q >> 3, fq = q & 7;
            const float4 va = *reinterpret_cast<const float4*>(
                &A[(size_t)(rowBase + r) * K + k0 + fq * 4]);
            As[r][fq * 4 + 0] = va.x;
            As[r][fq * 4 + 1] = va.y;
            As[r][fq * 4 + 2] = va.z;
            As[r][fq * 4 + 3] = va.w;
        }
        // Load B tile: 32x64 = 512 float4, 2 per thread
        #pragma unroll
        for (int i = 0; i < 2; ++i) {
            int q = tid + i * 256;
            int r = q >> 4, cq = q & 15;
            const float4 vb = *reinterpret_cast<const float4*>(
                &B[(size_t)(k0 + r) * N + colBase + cq * 4]);
            Bs[r][cq * 4 + 0] = vb.x;
            Bs[r][cq * 4 + 1] = vb.y;
            Bs[r][cq * 4 + 2] = vb.z;
            Bs[r][cq * 4 + 3] = vb.w;
        }
        __syncthreads();
        #pragma unroll
        for (int kk = 0; kk < BK; ++kk) {
            float a[4], b[4];
            #pragma unroll
            for (int i = 0; i < 4; ++i) a[i] = As[ty * 4 + i][kk];
            #pragma unroll
            for (int j = 0; j < 4; ++j) b[j] = Bs[kk][tx * 4 + j];
            #pragma unroll
            for (int i = 0; i < 4; ++i)
                #pragma unroll
                for (int j = 0; j < 4; ++j) acc[i][j] += a[i] * b[j];
        }
        __syncthreads();
    }
    #pragma unroll
    for (int i = 0; i < 4; ++i) {
        float4 v = make_float4(acc[i][0], acc[i][1], acc[i][2], acc[i][3]);
        *reinterpret_cast<float4*>(
            &C[(size_t)(rowBase + ty * 4 + i) * N + colBase + tx * 4]) = v;
    }
}

// ---------------------------------------------------------------------------
// Kernel 4: per-(n,h) attention dot products  a_src/a_dst
// ---------------------------------------------------------------------------
template <int FO>
__global__ __launch_bounds__(256) void adot_kernel(
    const float* __restrict__ Wh, const float* __restrict__ a,
    float* __restrict__ asrc, float* __restrict__ adst) {
    int t = blockIdx.x * blockDim.x + threadIdx.x;
    if (t >= NNODES * NHEADS) return;
    int n = t >> 2, h = t & 3;
    const float* row = Wh + (size_t)n * (NHEADS * FO) + h * FO;
    const float* ah = a + h * 2 * FO;
    float s = 0.f, d = 0.f;
    #pragma unroll 8
    for (int o = 0; o < FO; ++o) {
        float w = row[o];
        s += w * ah[o];
        d += w * ah[FO + o];
    }
    asrc[h * NNODES + n] = s;
    adst[h * NNODES + n] = d;
}

// ---------------------------------------------------------------------------
// Kernel 5: sparse softmax + aggregation + ELU. One wave per (n, h).
// ---------------------------------------------------------------------------
template <int FO>
__global__ __launch_bounds__(256) void agg_kernel(
    const float* __restrict__ Wh,
    const float* __restrict__ asrc, const float* __restrict__ adst,
    const int* __restrict__ nbr, const int* __restrict__ deg,
    float* __restrict__ out) {
    int wid = blockIdx.x * (blockDim.x >> 6) + (threadIdx.x >> 6);
    int lane = threadIdx.x & 63;
    if (wid >= NNODES * NHEADS) return;
    int n = wid >> 2, h = wid & 3;
    int dg = deg[n];
    const int* lst = nbr + n * NBR_STRIDE;
    float my_as = asrc[h * NNODES + n];

    int c0 = 0, c1 = 0;
    float e0 = -1e30f, e1 = -1e30f;
    if (lane < dg) {
        c0 = lst[lane];
        float e = my_as + adst[h * NNODES + c0];
        e0 = e >= 0.f ? e : 0.2f * e;
    }
    if (lane + 64 < dg) {
        c1 = lst[lane + 64];
        float e = my_as + adst[h * NNODES + c1];
        e1 = e >= 0.f ? e : 0.2f * e;
    }
    // wave max
    float m = fmaxf(e0, e1);
    #pragma unroll
    for (int s = 32; s; s >>= 1) m = fmaxf(m, __shfl_xor(m, s));
    float p0 = (lane < dg) ? __expf(e0 - m) : 0.f;
    float p1 = (lane + 64 < dg) ? __expf(e1 - m) : 0.f;
    float denom = p0 + p1;
    #pragma unroll
    for (int s = 32; s; s >>= 1) denom += __shfl_xor(denom, s);
    float inv = 1.0f / denom;

    constexpr int NPL = 64 / FO;   // neighbors handled per loop step
    int sub = lane / FO;           // which of the NPL neighbors this lane works on
    int dim = lane % FO;           // output dim
    float acc = 0.f;
    for (int k = 0; k < dg; k += NPL) {
        int kk = k + sub;
        int src = kk & 63;
        float wA = __shfl(p0, src);
        float wB = __shfl(p1, src);
        int colA = __shfl(c0, src);
        int colB = __shfl(c1, src);
        bool hi = kk >= 64;
        float w = hi ? wB : wA;
        int col = hi ? colB : colA;
        if (kk < dg) acc += w * Wh[(size_t)col * (NHEADS * FO) + h * FO + dim];
    }
    if (NPL == 2) acc += __shfl_xor(acc, 32);
    if (lane < FO) {
        float v = acc * inv;
        out[(size_t)n * (NHEADS * FO) + h * FO + dim] = v > 0.f ? v : expm1f(v);
    }
}

// ---------------------------------------------------------------------------
extern "C" void kernel_launch(void* const* d_in, const int* in_sizes, int n_in,
                              void* d_out, int out_size, void* d_ws, size_t ws_size,
                              hipStream_t stream) {
    const float* x   = (const float*)d_in[0];
    const float* adj = (const float*)d_in[1];
    const float* W1  = (const float*)d_in[2];
    const float* a1  = (const float*)d_in[3];
    const float* W2  = (const float*)d_in[4];
    const float* a2  = (const float*)d_in[5];
    float* out = (float*)d_out;

    char* p = (char*)d_ws;
    auto alloc = [&](size_t bytes) -> void* {
        void* r = (void*)p;
        p += (bytes + 255) & ~(size_t)255;
        return r;
    };
    int*   nbr = (int*)alloc((size_t)NNODES * NBR_STRIDE * 4);
    int*   deg = (int*)alloc((size_t)NNODES * 4);
    float* Wp1 = (float*)alloc((size_t)512 * 256 * 4);
    float* Wh1 = (float*)alloc((size_t)NNODES * 256 * 4);
    float* as1 = (float*)alloc((size_t)NHEADS * NNODES * 4);
    float* ad1 = (float*)alloc((size_t)NHEADS * NNODES * 4);
    float* h1  = (float*)alloc((size_t)NNODES * 256 * 4);
    float* Wp2 = (float*)alloc((size_t)256 * 128 * 4);
    float* Wh2 = (float*)alloc((size_t)NNODES * 128 * 4);
    float* as2 = (float*)alloc((size_t)NHEADS * NNODES * 4);
    float* ad2 = (float*)alloc((size_t)NHEADS * NNODES * 4);

    // ---- shared: neighbor lists ----
    build_nbr_kernel<<<dim3(NNODES / 4), dim3(256), 0, stream>>>(adj, nbr, deg);

    // ---- layer 1 ----
    pack_w_kernel<<<dim3(512 * 256 / 256), dim3(256), 0, stream>>>(W1, Wp1, 512, 64);
    gemm_f32_kernel<<<dim3(4096 / 64, 256 / 64), dim3(256), 0, stream>>>(
        x, Wp1, Wh1, 4096, 256, 512);
    adot_kernel<64><<<dim3(NNODES * NHEADS / 256), dim3(256), 0, stream>>>(
        Wh1, a1, as1, ad1);
    agg_kernel<64><<<dim3(NNODES * NHEADS / 4), dim3(256), 0, stream>>>(
        Wh1, as1, ad1, nbr, deg, h1);

    // ---- layer 2 ----
    pack_w_kernel<<<dim3(256 * 128 / 256), dim3(256), 0, stream>>>(W2, Wp2, 256, 32);
    gemm_f32_kernel<<<dim3(4096 / 64, 128 / 64), dim3(256), 0, stream>>>(
        h1, Wp2, Wh2, 4096, 128, 256);
    adot_kernel<32><<<dim3(NNODES * NHEADS / 256), dim3(256), 0, stream>>>(
        Wh2, a2, as2, ad2);
    agg_kernel<32><<<dim3(NNODES * NHEADS / 4), dim3(256), 0, stream>>>(
        Wh2, as2, ad2, nbr, deg, out);
}

// Round 2
// 100.606 us; speedup vs baseline: 1.4520x; 1.4520x over previous
//
#include <hip/hip_runtime.h>
#include <hip/hip_bf16.h>
#include <cstdint>
#include <cstddef>

#define NNODES 4096
#define NHEADS 4
#define NBR_STRIDE 128

// ---------------------------------------------------------------------------
// Kernel 1: build neighbor lists (deterministic wave-ballot compaction).
// One wave per row; float4 loads -> 16 iterations of 256 columns each.
// Compacts indices of adj>0 in column order via 4 ballots + prefix popcount.
// ---------------------------------------------------------------------------
__global__ __launch_bounds__(256) void build_nbr_kernel(
    const float* __restrict__ adj, int* __restrict__ nbr, int* __restrict__ deg) {
    int wave = threadIdx.x >> 6;
    int lane = threadIdx.x & 63;
    int row = blockIdx.x * 4 + wave;
    const float4* arow = reinterpret_cast<const float4*>(adj + (size_t)row * NNODES);
    unsigned long long lt = (1ull << lane) - 1ull;
    int base = 0;
    #pragma unroll 4
    for (int it = 0; it < NNODES / 256; ++it) {
        float4 v = arow[it * 64 + lane];
        bool b0 = v.x > 0.f, b1 = v.y > 0.f, b2 = v.z > 0.f, b3 = v.w > 0.f;
        unsigned long long m0 = __ballot(b0);
        unsigned long long m1 = __ballot(b1);
        unsigned long long m2 = __ballot(b2);
        unsigned long long m3 = __ballot(b3);
        int pre = __popcll(m0 & lt) + __popcll(m1 & lt) +
                  __popcll(m2 & lt) + __popcll(m3 & lt);
        int pos = base + pre;
        int colb = it * 256 + lane * 4;
        if (b0) { if (pos < NBR_STRIDE) nbr[row * NBR_STRIDE + pos] = colb;     pos++; }
        if (b1) { if (pos < NBR_STRIDE) nbr[row * NBR_STRIDE + pos] = colb + 1; pos++; }
        if (b2) { if (pos < NBR_STRIDE) nbr[row * NBR_STRIDE + pos] = colb + 2; pos++; }
        if (b3) { if (pos < NBR_STRIDE) nbr[row * NBR_STRIDE + pos] = colb + 3; pos++; }
        base += __popcll(m0) + __popcll(m1) + __popcll(m2) + __popcll(m3);
    }
    if (lane == 0) deg[row] = base < NBR_STRIDE ? base : NBR_STRIDE;
}

// ---------------------------------------------------------------------------
// Kernel 2: pack W[h][f][o] -> Wp[f][h*FO+o] (row-major K x (4*FO))
// ---------------------------------------------------------------------------
__global__ __launch_bounds__(256) void pack_w_kernel(
    const float* __restrict__ W, float* __restrict__ Wp, int K, int FO) {
    int idx = blockIdx.x * blockDim.x + threadIdx.x;
    int ncols = NHEADS * FO;
    if (idx >= K * ncols) return;
    int f = idx / ncols;
    int c = idx - f * ncols;
    int h = c / FO;
    int o = c - h * FO;
    Wp[idx] = W[((size_t)h * K + f) * FO + o];
}

// ---------------------------------------------------------------------------
// Kernel 3: f32 tiled GEMM  C[M,N] = A[M,K] * B[K,N]   (row-major all)
// BM=BN=64, BK=32, 256 threads, 4x4 per thread.
// ---------------------------------------------------------------------------
__global__ __launch_bounds__(256) void gemm_f32_kernel(
    const float* __restrict__ A, const float* __restrict__ B,
    float* __restrict__ C, int M, int N, int K) {
    constexpr int BM = 64, BN = 64, BK = 32;
    __shared__ float As[BM][BK + 4];
    __shared__ float Bs[BK][BN + 4];
    int tid = threadIdx.x;
    int tx = tid & 15, ty = tid >> 4;
    int rowBase = blockIdx.x * BM;
    int colBase = blockIdx.y * BN;
    float acc[4][4] = {};
    for (int k0 = 0; k0 < K; k0 += BK) {
        #pragma unroll
        for (int i = 0; i < 2; ++i) {
            int q = tid + i * 256;
            int r = q >> 3, fq = q & 7;
            const float4 va = *reinterpret_cast<const float4*>(
                &A[(size_t)(rowBase + r) * K + k0 + fq * 4]);
            As[r][fq * 4 + 0] = va.x;
            As[r][fq * 4 + 1] = va.y;
            As[r][fq * 4 + 2] = va.z;
            As[r][fq * 4 + 3] = va.w;
        }
        #pragma unroll
        for (int i = 0; i < 2; ++i) {
            int q = tid + i * 256;
            int r = q >> 4, cq = q & 15;
            const float4 vb = *reinterpret_cast<const float4*>(
                &B[(size_t)(k0 + r) * N + colBase + cq * 4]);
            Bs[r][cq * 4 + 0] = vb.x;
            Bs[r][cq * 4 + 1] = vb.y;
            Bs[r][cq * 4 + 2] = vb.z;
            Bs[r][cq * 4 + 3] = vb.w;
        }
        __syncthreads();
        #pragma unroll
        for (int kk = 0; kk < BK; ++kk) {
            float a[4], b[4];
            #pragma unroll
            for (int i = 0; i < 4; ++i) a[i] = As[ty * 4 + i][kk];
            #pragma unroll
            for (int j = 0; j < 4; ++j) b[j] = Bs[kk][tx * 4 + j];
            #pragma unroll
            for (int i = 0; i < 4; ++i)
                #pragma unroll
                for (int j = 0; j < 4; ++j) acc[i][j] += a[i] * b[j];
        }
        __syncthreads();
    }
    #pragma unroll
    for (int i = 0; i < 4; ++i) {
        float4 v = make_float4(acc[i][0], acc[i][1], acc[i][2], acc[i][3]);
        *reinterpret_cast<float4*>(
            &C[(size_t)(rowBase + ty * 4 + i) * N + colBase + tx * 4]) = v;
    }
}

// ---------------------------------------------------------------------------
// Kernel 4: per-(n,h) attention dot products  a_src/a_dst
// ---------------------------------------------------------------------------
template <int FO>
__global__ __launch_bounds__(256) void adot_kernel(
    const float* __restrict__ Wh, const float* __restrict__ a,
    float* __restrict__ asrc, float* __restrict__ adst) {
    int t = blockIdx.x * blockDim.x + threadIdx.x;
    if (t >= NNODES * NHEADS) return;
    int n = t >> 2, h = t & 3;
    const float* row = Wh + (size_t)n * (NHEADS * FO) + h * FO;
    const float* ah = a + h * 2 * FO;
    float s = 0.f, d = 0.f;
    #pragma unroll 8
    for (int o = 0; o < FO; ++o) {
        float w = row[o];
        s += w * ah[o];
        d += w * ah[FO + o];
    }
    asrc[h * NNODES + n] = s;
    adst[h * NNODES + n] = d;
}

// ---------------------------------------------------------------------------
// Kernel 5: sparse softmax + aggregation + ELU. One wave per (n, h).
// Normalized weights + column indices staged in LDS as float2; main gather
// loop unrolled x8 so 8 independent loads are in flight per wave.
// ---------------------------------------------------------------------------
template <int FO>
__global__ __launch_bounds__(256) void agg_kernel(
    const float* __restrict__ Wh,
    const float* __restrict__ asrc, const float* __restrict__ adst,
    const int* __restrict__ nbr, const int* __restrict__ deg,
    float* __restrict__ out) {
    __shared__ float2 sw[4][NBR_STRIDE];
    int wslot = threadIdx.x >> 6;
    int lane = threadIdx.x & 63;
    int wid = blockIdx.x * 4 + wslot;
    int n = wid >> 2, h = wid & 3;
    int dg = deg[n];
    const int* lst = nbr + n * NBR_STRIDE;
    float my_as = asrc[h * NNODES + n];

    int c0 = 0, c1 = 0;
    float e0 = -1e30f, e1 = -1e30f;
    if (lane < dg) {
        c0 = lst[lane];
        float e = my_as + adst[h * NNODES + c0];
        e0 = e >= 0.f ? e : 0.2f * e;
    }
    if (lane + 64 < dg) {
        c1 = lst[lane + 64];
        float e = my_as + adst[h * NNODES + c1];
        e1 = e >= 0.f ? e : 0.2f * e;
    }
    float m = fmaxf(e0, e1);
    #pragma unroll
    for (int s = 32; s; s >>= 1) m = fmaxf(m, __shfl_xor(m, s));
    float p0 = (lane < dg) ? __expf(e0 - m) : 0.f;
    float p1 = (lane + 64 < dg) ? __expf(e1 - m) : 0.f;
    float denom = p0 + p1;
    #pragma unroll
    for (int s = 32; s; s >>= 1) denom += __shfl_xor(denom, s);
    float inv = 1.0f / denom;

    if (lane < dg)      sw[wslot][lane]      = make_float2(p0 * inv, __int_as_float(c0));
    if (lane + 64 < dg) sw[wslot][lane + 64] = make_float2(p1 * inv, __int_as_float(c1));
    __syncthreads();

    constexpr int NPL = 64 / FO;          // neighbors per loop step (1 or 2)
    int sub = (FO == 64) ? 0 : (lane >> 5);
    int dim = lane & (FO - 1);
    const float* whp = Wh + h * FO + dim;  // stride NHEADS*FO per node
    constexpr int STRIDE = NHEADS * FO;

    float acc = 0.f;
    int main_n = (dg / (8 * NPL)) * (8 * NPL);
    int k = 0;
    for (; k < main_n; k += 8 * NPL) {
        #pragma unroll
        for (int u = 0; u < 8; ++u) {
            float2 w = sw[wslot][k + u * NPL + sub];
            int col = __float_as_int(w.y);
            acc += w.x * whp[(size_t)col * STRIDE];
        }
    }
    for (; k < dg; k += NPL) {
        if (k + sub < dg) {
            float2 w = sw[wslot][k + sub];
            int col = __float_as_int(w.y);
            acc += w.x * whp[(size_t)col * STRIDE];
        }
    }
    if (NPL == 2) acc += __shfl_xor(acc, 32);
    if (lane < FO) {
        float v = acc;
        out[(size_t)n * STRIDE + h * FO + dim] = v > 0.f ? v : expm1f(v);
    }
}

// ---------------------------------------------------------------------------
extern "C" void kernel_launch(void* const* d_in, const int* in_sizes, int n_in,
                              void* d_out, int out_size, void* d_ws, size_t ws_size,
                              hipStream_t stream) {
    const float* x   = (const float*)d_in[0];
    const float* adj = (const float*)d_in[1];
    const float* W1  = (const float*)d_in[2];
    const float* a1  = (const float*)d_in[3];
    const float* W2  = (const float*)d_in[4];
    const float* a2  = (const float*)d_in[5];
    float* out = (float*)d_out;

    char* p = (char*)d_ws;
    auto alloc = [&](size_t bytes) -> void* {
        void* r = (void*)p;
        p += (bytes + 255) & ~(size_t)255;
        return r;
    };
    int*   nbr = (int*)alloc((size_t)NNODES * NBR_STRIDE * 4);
    int*   deg = (int*)alloc((size_t)NNODES * 4);
    float* Wp1 = (float*)alloc((size_t)512 * 256 * 4);
    float* Wh1 = (float*)alloc((size_t)NNODES * 256 * 4);
    float* as1 = (float*)alloc((size_t)NHEADS * NNODES * 4);
    float* ad1 = (float*)alloc((size_t)NHEADS * NNODES * 4);
    float* h1  = (float*)alloc((size_t)NNODES * 256 * 4);
    float* Wp2 = (float*)alloc((size_t)256 * 128 * 4);
    float* Wh2 = (float*)alloc((size_t)NNODES * 128 * 4);
    float* as2 = (float*)alloc((size_t)NHEADS * NNODES * 4);
    float* ad2 = (float*)alloc((size_t)NHEADS * NNODES * 4);

    // ---- shared: neighbor lists ----
    build_nbr_kernel<<<dim3(NNODES / 4), dim3(256), 0, stream>>>(adj, nbr, deg);

    // ---- layer 1 ----
    pack_w_kernel<<<dim3(512 * 256 / 256), dim3(256), 0, stream>>>(W1, Wp1, 512, 64);
    gemm_f32_kernel<<<dim3(4096 / 64, 256 / 64), dim3(256), 0, stream>>>(
        x, Wp1, Wh1, 4096, 256, 512);
    adot_kernel<64><<<dim3(NNODES * NHEADS / 256), dim3(256), 0, stream>>>(
        Wh1, a1, as1, ad1);
    agg_kernel<64><<<dim3(NNODES * NHEADS / 4), dim3(256), 0, stream>>>(
        Wh1, as1, ad1, nbr, deg, h1);

    // ---- layer 2 ----
    pack_w_kernel<<<dim3(256 * 128 / 256), dim3(256), 0, stream>>>(W2, Wp2, 256, 32);
    gemm_f32_kernel<<<dim3(4096 / 64, 128 / 64), dim3(256), 0, stream>>>(
        h1, Wp2, Wh2, 4096, 128, 256);
    adot_kernel<32><<<dim3(NNODES * NHEADS / 256), dim3(256), 0, stream>>>(
        Wh2, a2, as2, ad2);
    agg_kernel<32><<<dim3(NNODES * NHEADS / 4), dim3(256), 0, stream>>>(
        Wh2, as2, ad2, nbr, deg, out);
}

// Round 3
// 91.432 us; speedup vs baseline: 1.5977x; 1.1003x over previous
//
#include <hip/hip_runtime.h>
#include <hip/hip_bf16.h>
#include <cstdint>
#include <cstddef>

#define NNODES 4096
#define NHEADS 4
#define NBR_STRIDE 128

typedef __attribute__((ext_vector_type(8))) short bf16x8v;
typedef __attribute__((ext_vector_type(4))) float f32x4;

__device__ inline unsigned short bf16_rn(float f) {
    unsigned int u = __float_as_uint(f);
    u += 0x7FFFu + ((u >> 16) & 1u);
    return (unsigned short)(u >> 16);
}
__device__ inline float bf16_f32(unsigned short s) {
    return __uint_as_float(((unsigned int)s) << 16);
}

// ---------------------------------------------------------------------------
// Kernel 1: build neighbor lists (deterministic wave-ballot compaction).
// ---------------------------------------------------------------------------
__global__ __launch_bounds__(256) void build_nbr_kernel(
    const float* __restrict__ adj, int* __restrict__ nbr, int* __restrict__ deg) {
    int wave = threadIdx.x >> 6;
    int lane = threadIdx.x & 63;
    int row = blockIdx.x * 4 + wave;
    const float4* arow = reinterpret_cast<const float4*>(adj + (size_t)row * NNODES);
    unsigned long long lt = (1ull << lane) - 1ull;
    int base = 0;
    #pragma unroll 4
    for (int it = 0; it < NNODES / 256; ++it) {
        float4 v = arow[it * 64 + lane];
        bool b0 = v.x > 0.f, b1 = v.y > 0.f, b2 = v.z > 0.f, b3 = v.w > 0.f;
        unsigned long long m0 = __ballot(b0);
        unsigned long long m1 = __ballot(b1);
        unsigned long long m2 = __ballot(b2);
        unsigned long long m3 = __ballot(b3);
        int pre = __popcll(m0 & lt) + __popcll(m1 & lt) +
                  __popcll(m2 & lt) + __popcll(m3 & lt);
        int pos = base + pre;
        int colb = it * 256 + lane * 4;
        if (b0) { if (pos < NBR_STRIDE) nbr[row * NBR_STRIDE + pos] = colb;     pos++; }
        if (b1) { if (pos < NBR_STRIDE) nbr[row * NBR_STRIDE + pos] = colb + 1; pos++; }
        if (b2) { if (pos < NBR_STRIDE) nbr[row * NBR_STRIDE + pos] = colb + 2; pos++; }
        if (b3) { if (pos < NBR_STRIDE) nbr[row * NBR_STRIDE + pos] = colb + 3; pos++; }
        base += __popcll(m0) + __popcll(m1) + __popcll(m2) + __popcll(m3);
    }
    if (lane == 0) deg[row] = base < NBR_STRIDE ? base : NBR_STRIDE;
}

// ---------------------------------------------------------------------------
// Kernel 2a: split A[M,K] f32 -> Ap[M,3K] bf16 laid out [hi | hi | lo]
// ---------------------------------------------------------------------------
template <int K>
__global__ __launch_bounds__(256) void split_a_kernel(
    const float* __restrict__ A, unsigned short* __restrict__ Ap, int M) {
    int t = blockIdx.x * 256 + threadIdx.x;
    constexpr int perRow = K / 4;
    if (t >= M * perRow) return;
    int m = t / perRow;
    int c4 = (t - m * perRow) * 4;
    float4 v = *reinterpret_cast<const float4*>(&A[(size_t)m * K + c4]);
    ushort4 hi, lo;
    hi.x = bf16_rn(v.x); lo.x = bf16_rn(v.x - bf16_f32(hi.x));
    hi.y = bf16_rn(v.y); lo.y = bf16_rn(v.y - bf16_f32(hi.y));
    hi.z = bf16_rn(v.z); lo.z = bf16_rn(v.z - bf16_f32(hi.z));
    hi.w = bf16_rn(v.w); lo.w = bf16_rn(v.w - bf16_f32(hi.w));
    size_t base = (size_t)m * 3 * K;
    *reinterpret_cast<ushort4*>(&Ap[base + c4]) = hi;
    *reinterpret_cast<ushort4*>(&Ap[base + K + c4]) = hi;
    *reinterpret_cast<ushort4*>(&Ap[base + 2 * K + c4]) = lo;
}

// ---------------------------------------------------------------------------
// Kernel 2b: W[H][K][FO] f32 -> Bt[N=H*FO][3K] bf16, layout [hi | lo | hi]
// (B' transposed so GEMM fragment reads are contiguous in k)
// ---------------------------------------------------------------------------
template <int K, int FO>
__global__ __launch_bounds__(256) void split_b_kernel(
    const float* __restrict__ W, unsigned short* __restrict__ Bt) {
    constexpr int NCOL = NHEADS * FO;
    int t = blockIdx.x * 256 + threadIdx.x;
    if (t >= NCOL * K) return;
    int n = t / K, k = t - n * K;
    int h = n / FO, o = n - h * FO;
    float v = W[((size_t)h * K + k) * FO + o];
    unsigned short hi = bf16_rn(v);
    unsigned short lo = bf16_rn(v - bf16_f32(hi));
    size_t base = (size_t)n * 3 * K;
    Bt[base + k] = hi;
    Bt[base + K + k] = lo;
    Bt[base + 2 * K + k] = hi;
}

// ---------------------------------------------------------------------------
// Kernel 3: MFMA GEMM  C[M,N] = Ap[M,K3] * Bt[N,K3]^T   (f32 out)
// BM=32, BN=64, BK=64; 4 waves, each wave = 16 rows x 32 cols (2 frags).
// LDS rows padded +8 ushorts (16B) -> <=2-way bank aliasing on b128 reads.
// ---------------------------------------------------------------------------
template <int K3>
__global__ __launch_bounds__(256) void gemm_mfma_kernel(
    const unsigned short* __restrict__ A, const unsigned short* __restrict__ Bt,
    float* __restrict__ C, int N) {
    constexpr int BM = 32, BN = 64, BK = 64, PAD = 8;
    __shared__ unsigned short Al[BM][BK + PAD];
    __shared__ unsigned short Bl[BN][BK + PAD];
    int tid = threadIdx.x;
    int wave = tid >> 6, lane = tid & 63;
    int rowBase = blockIdx.x * BM;
    int colBase = blockIdx.y * BN;
    int wr = wave >> 1, wc = wave & 1;
    int lr = lane & 15, lk = lane >> 4;
    f32x4 acc0 = {0.f, 0.f, 0.f, 0.f};
    f32x4 acc1 = {0.f, 0.f, 0.f, 0.f};
    int ar = tid >> 3;            // 0..31
    int ac = (tid & 7) * 8;       // 0..56, 8-ushort chunks
    for (int k0 = 0; k0 < K3; k0 += BK) {
        uint4 av  = *reinterpret_cast<const uint4*>(&A[(size_t)(rowBase + ar) * K3 + k0 + ac]);
        uint4 bv0 = *reinterpret_cast<const uint4*>(&Bt[(size_t)(colBase + ar) * K3 + k0 + ac]);
        uint4 bv1 = *reinterpret_cast<const uint4*>(&Bt[(size_t)(colBase + 32 + ar) * K3 + k0 + ac]);
        __syncthreads();   // previous iteration's readers done
        *reinterpret_cast<uint4*>(&Al[ar][ac]) = av;
        *reinterpret_cast<uint4*>(&Bl[ar][ac]) = bv0;
        *reinterpret_cast<uint4*>(&Bl[32 + ar][ac]) = bv1;
        __syncthreads();
        #pragma unroll
        for (int ks = 0; ks < 2; ++ks) {
            int kb = ks * 32 + lk * 8;
            bf16x8v a  = *reinterpret_cast<const bf16x8v*>(&Al[wr * 16 + lr][kb]);
            bf16x8v b0 = *reinterpret_cast<const bf16x8v*>(&Bl[wc * 32 + lr][kb]);
            bf16x8v b1 = *reinterpret_cast<const bf16x8v*>(&Bl[wc * 32 + 16 + lr][kb]);
            acc0 = __builtin_amdgcn_mfma_f32_16x16x32_bf16(a, b0, acc0, 0, 0, 0);
            acc1 = __builtin_amdgcn_mfma_f32_16x16x32_bf16(a, b1, acc1, 0, 0, 0);
        }
    }
    int crow = rowBase + wr * 16 + lk * 4;
    int ccol = colBase + wc * 32 + lr;
    #pragma unroll
    for (int r = 0; r < 4; ++r) {
        C[(size_t)(crow + r) * N + ccol]      = acc0[r];
        C[(size_t)(crow + r) * N + ccol + 16] = acc1[r];
    }
}

// ---------------------------------------------------------------------------
// Kernel 4: per-(n,h) attention dot products  a_src/a_dst
// ---------------------------------------------------------------------------
template <int FO>
__global__ __launch_bounds__(256) void adot_kernel(
    const float* __restrict__ Wh, const float* __restrict__ a,
    float* __restrict__ asrc, float* __restrict__ adst) {
    int t = blockIdx.x * blockDim.x + threadIdx.x;
    if (t >= NNODES * NHEADS) return;
    int n = t >> 2, h = t & 3;
    const float* row = Wh + (size_t)n * (NHEADS * FO) + h * FO;
    const float* ah = a + h * 2 * FO;
    float s = 0.f, d = 0.f;
    #pragma unroll 8
    for (int o = 0; o < FO; ++o) {
        float w = row[o];
        s += w * ah[o];
        d += w * ah[FO + o];
    }
    asrc[h * NNODES + n] = s;
    adst[h * NNODES + n] = d;
}

// ---------------------------------------------------------------------------
// Kernel 5: sparse softmax + aggregation + ELU. One wave per (n, h).
// ---------------------------------------------------------------------------
template <int FO>
__global__ __launch_bounds__(256) void agg_kernel(
    const float* __restrict__ Wh,
    const float* __restrict__ asrc, const float* __restrict__ adst,
    const int* __restrict__ nbr, const int* __restrict__ deg,
    float* __restrict__ out) {
    __shared__ float2 sw[4][NBR_STRIDE];
    int wslot = threadIdx.x >> 6;
    int lane = threadIdx.x & 63;
    int wid = blockIdx.x * 4 + wslot;
    int n = wid >> 2, h = wid & 3;
    int dg = deg[n];
    const int* lst = nbr + n * NBR_STRIDE;
    float my_as = asrc[h * NNODES + n];

    int c0 = 0, c1 = 0;
    float e0 = -1e30f, e1 = -1e30f;
    if (lane < dg) {
        c0 = lst[lane];
        float e = my_as + adst[h * NNODES + c0];
        e0 = e >= 0.f ? e : 0.2f * e;
    }
    if (lane + 64 < dg) {
        c1 = lst[lane + 64];
        float e = my_as + adst[h * NNODES + c1];
        e1 = e >= 0.f ? e : 0.2f * e;
    }
    float m = fmaxf(e0, e1);
    #pragma unroll
    for (int s = 32; s; s >>= 1) m = fmaxf(m, __shfl_xor(m, s));
    float p0 = (lane < dg) ? __expf(e0 - m) : 0.f;
    float p1 = (lane + 64 < dg) ? __expf(e1 - m) : 0.f;
    float denom = p0 + p1;
    #pragma unroll
    for (int s = 32; s; s >>= 1) denom += __shfl_xor(denom, s);
    float inv = 1.0f / denom;

    if (lane < dg)      sw[wslot][lane]      = make_float2(p0 * inv, __int_as_float(c0));
    if (lane + 64 < dg) sw[wslot][lane + 64] = make_float2(p1 * inv, __int_as_float(c1));
    __syncthreads();

    constexpr int NPL = 64 / FO;
    int sub = (FO == 64) ? 0 : (lane >> 5);
    int dim = lane & (FO - 1);
    const float* whp = Wh + h * FO + dim;
    constexpr int STRIDE = NHEADS * FO;

    float acc = 0.f;
    int main_n = (dg / (8 * NPL)) * (8 * NPL);
    int k = 0;
    for (; k < main_n; k += 8 * NPL) {
        #pragma unroll
        for (int u = 0; u < 8; ++u) {
            float2 w = sw[wslot][k + u * NPL + sub];
            int col = __float_as_int(w.y);
            acc += w.x * whp[(size_t)col * STRIDE];
        }
    }
    for (; k < dg; k += NPL) {
        if (k + sub < dg) {
            float2 w = sw[wslot][k + sub];
            int col = __float_as_int(w.y);
            acc += w.x * whp[(size_t)col * STRIDE];
        }
    }
    if (NPL == 2) acc += __shfl_xor(acc, 32);
    if (lane < FO) {
        float v = acc;
        out[(size_t)n * STRIDE + h * FO + dim] = v > 0.f ? v : expm1f(v);
    }
}

// ---------------------------------------------------------------------------
extern "C" void kernel_launch(void* const* d_in, const int* in_sizes, int n_in,
                              void* d_out, int out_size, void* d_ws, size_t ws_size,
                              hipStream_t stream) {
    const float* x   = (const float*)d_in[0];
    const float* adj = (const float*)d_in[1];
    const float* W1  = (const float*)d_in[2];
    const float* a1  = (const float*)d_in[3];
    const float* W2  = (const float*)d_in[4];
    const float* a2  = (const float*)d_in[5];
    float* out = (float*)d_out;

    char* p = (char*)d_ws;
    auto alloc = [&](size_t bytes) -> void* {
        void* r = (void*)p;
        p += (bytes + 255) & ~(size_t)255;
        return r;
    };
    int*   nbr = (int*)alloc((size_t)NNODES * NBR_STRIDE * 4);
    int*   deg = (int*)alloc((size_t)NNODES * 4);
    unsigned short* A1p = (unsigned short*)alloc((size_t)NNODES * 1536 * 2);
    unsigned short* B1t = (unsigned short*)alloc((size_t)256 * 1536 * 2);
    float* Wh1 = (float*)alloc((size_t)NNODES * 256 * 4);
    float* as1 = (float*)alloc((size_t)NHEADS * NNODES * 4);
    float* ad1 = (float*)alloc((size_t)NHEADS * NNODES * 4);
    float* h1  = (float*)alloc((size_t)NNODES * 256 * 4);
    unsigned short* A2p = (unsigned short*)alloc((size_t)NNODES * 768 * 2);
    unsigned short* B2t = (unsigned short*)alloc((size_t)128 * 768 * 2);
    float* Wh2 = (float*)alloc((size_t)NNODES * 128 * 4);
    float* as2 = (float*)alloc((size_t)NHEADS * NNODES * 4);
    float* ad2 = (float*)alloc((size_t)NHEADS * NNODES * 4);

    // ---- shared: neighbor lists ----
    build_nbr_kernel<<<dim3(NNODES / 4), dim3(256), 0, stream>>>(adj, nbr, deg);

    // ---- layer 1 ----
    split_a_kernel<512><<<dim3(NNODES * 128 / 256), dim3(256), 0, stream>>>(x, A1p, NNODES);
    split_b_kernel<512, 64><<<dim3(256 * 512 / 256), dim3(256), 0, stream>>>(W1, B1t);
    gemm_mfma_kernel<1536><<<dim3(NNODES / 32, 256 / 64), dim3(256), 0, stream>>>(
        A1p, B1t, Wh1, 256);
    adot_kernel<64><<<dim3(NNODES * NHEADS / 256), dim3(256), 0, stream>>>(
        Wh1, a1, as1, ad1);
    agg_kernel<64><<<dim3(NNODES * NHEADS / 4), dim3(256), 0, stream>>>(
        Wh1, as1, ad1, nbr, deg, h1);

    // ---- layer 2 ----
    split_a_kernel<256><<<dim3(NNODES * 64 / 256), dim3(256), 0, stream>>>(h1, A2p, NNODES);
    split_b_kernel<256, 32><<<dim3(128 * 256 / 256), dim3(256), 0, stream>>>(W2, B2t);
    gemm_mfma_kernel<768><<<dim3(NNODES / 32, 128 / 64), dim3(256), 0, stream>>>(
        A2p, B2t, Wh2, 128);
    adot_kernel<32><<<dim3(NNODES * NHEADS / 256), dim3(256), 0, stream>>>(
        Wh2, a2, as2, ad2);
    agg_kernel<32><<<dim3(NNODES * NHEADS / 4), dim3(256), 0, stream>>>(
        Wh2, as2, ad2, nbr, deg, out);
}

// Round 4
// 77.902 us; speedup vs baseline: 1.8752x; 1.1737x over previous
//
#include <hip/hip_runtime.h>
#include <hip/hip_bf16.h>
#include <cstdint>
#include <cstddef>

#define NNODES 4096
#define NHEADS 4
#define NBR_STRIDE 128

typedef __attribute__((ext_vector_type(8))) short bf16x8v;
typedef __attribute__((ext_vector_type(4))) float f32x4;

__device__ inline unsigned short bf16_rn(float f) {
    unsigned int u = __float_as_uint(f);
    u += 0x7FFFu + ((u >> 16) & 1u);
    return (unsigned short)(u >> 16);
}
__device__ inline float bf16_f32(unsigned short s) {
    return __uint_as_float(((unsigned int)s) << 16);
}

// ---------------------------------------------------------------------------
// Kernel 1: build neighbor lists (deterministic wave-ballot compaction).
// ---------------------------------------------------------------------------
__global__ __launch_bounds__(256) void build_nbr_kernel(
    const float* __restrict__ adj, int* __restrict__ nbr, int* __restrict__ deg) {
    int wave = threadIdx.x >> 6;
    int lane = threadIdx.x & 63;
    int row = blockIdx.x * 4 + wave;
    const float4* arow = reinterpret_cast<const float4*>(adj + (size_t)row * NNODES);
    unsigned long long lt = (1ull << lane) - 1ull;
    int base = 0;
    #pragma unroll 4
    for (int it = 0; it < NNODES / 256; ++it) {
        float4 v = arow[it * 64 + lane];
        bool b0 = v.x > 0.f, b1 = v.y > 0.f, b2 = v.z > 0.f, b3 = v.w > 0.f;
        unsigned long long m0 = __ballot(b0);
        unsigned long long m1 = __ballot(b1);
        unsigned long long m2 = __ballot(b2);
        unsigned long long m3 = __ballot(b3);
        int pre = __popcll(m0 & lt) + __popcll(m1 & lt) +
                  __popcll(m2 & lt) + __popcll(m3 & lt);
        int pos = base + pre;
        int colb = it * 256 + lane * 4;
        if (b0) { if (pos < NBR_STRIDE) nbr[row * NBR_STRIDE + pos] = colb;     pos++; }
        if (b1) { if (pos < NBR_STRIDE) nbr[row * NBR_STRIDE + pos] = colb + 1; pos++; }
        if (b2) { if (pos < NBR_STRIDE) nbr[row * NBR_STRIDE + pos] = colb + 2; pos++; }
        if (b3) { if (pos < NBR_STRIDE) nbr[row * NBR_STRIDE + pos] = colb + 3; pos++; }
        base += __popcll(m0) + __popcll(m1) + __popcll(m2) + __popcll(m3);
    }
    if (lane == 0) deg[row] = base < NBR_STRIDE ? base : NBR_STRIDE;
}

// ---------------------------------------------------------------------------
// Kernel 2: pack BOTH layers' W -> transposed hi/lo bf16  Bt[N][K]
// layer1: n in [0,256), K=512 ; layer2: n in [0,128), K=256
// ---------------------------------------------------------------------------
__global__ __launch_bounds__(256) void pack_b_both_kernel(
    const float* __restrict__ W1, const float* __restrict__ W2,
    unsigned short* __restrict__ B1h, unsigned short* __restrict__ B1l,
    unsigned short* __restrict__ B2h, unsigned short* __restrict__ B2l) {
    int t = blockIdx.x * 256 + threadIdx.x;
    if (t < 256 * 512) {
        int n = t >> 9, k = t & 511;
        int h = n >> 6, o = n & 63;
        float v = W1[((size_t)h * 512 + k) * 64 + o];
        unsigned short hi = bf16_rn(v);
        B1h[t] = hi;
        B1l[t] = bf16_rn(v - bf16_f32(hi));
    } else {
        int u = t - 256 * 512;
        if (u < 128 * 256) {
            int n = u >> 8, k = u & 255;
            int h = n >> 5, o = n & 31;
            float v = W2[((size_t)h * 256 + k) * 32 + o];
            unsigned short hi = bf16_rn(v);
            B2h[u] = hi;
            B2l[u] = bf16_rn(v - bf16_f32(hi));
        }
    }
}

// ---------------------------------------------------------------------------
// Kernel 3: MFMA GEMM with in-kernel precision split.
// C[M,N] = A[M,K](f32) * Bt[N,K]^T via hi*hi + hi*lo + lo*hi (bf16 MFMA).
// BM=32, BN=64, BK=64; 4 waves, each wave = 16 rows x 32 cols (2 frags).
// ---------------------------------------------------------------------------
template <int K, int N>
__global__ __launch_bounds__(256) void gemm_split_kernel(
    const float* __restrict__ A,
    const unsigned short* __restrict__ Bh, const unsigned short* __restrict__ Bl,
    float* __restrict__ C) {
    constexpr int BM = 32, BN = 64, BK = 64, LP = BK + 8;
    __shared__ unsigned short Alh[BM][LP], All[BM][LP];
    __shared__ unsigned short Blh[BN][LP], Bll[BN][LP];
    int tid = threadIdx.x;
    int wave = tid >> 6, lane = tid & 63;
    int rowBase = blockIdx.x * BM;
    int colBase = blockIdx.y * BN;
    int wr = wave >> 1, wc = wave & 1;
    int lr = lane & 15, lk = lane >> 4;
    f32x4 acc0 = {0.f, 0.f, 0.f, 0.f};
    f32x4 acc1 = {0.f, 0.f, 0.f, 0.f};
    int ar = tid >> 3;            // 0..31
    int ac = (tid & 7) * 8;       // 8-elem chunks
    for (int k0 = 0; k0 < K; k0 += BK) {
        float4 a0 = *reinterpret_cast<const float4*>(&A[(size_t)(rowBase + ar) * K + k0 + ac]);
        float4 a1 = *reinterpret_cast<const float4*>(&A[(size_t)(rowBase + ar) * K + k0 + ac + 4]);
        uint4 bh0 = *reinterpret_cast<const uint4*>(&Bh[(size_t)(colBase + ar) * K + k0 + ac]);
        uint4 bl0 = *reinterpret_cast<const uint4*>(&Bl[(size_t)(colBase + ar) * K + k0 + ac]);
        uint4 bh1 = *reinterpret_cast<const uint4*>(&Bh[(size_t)(colBase + 32 + ar) * K + k0 + ac]);
        uint4 bl1 = *reinterpret_cast<const uint4*>(&Bl[(size_t)(colBase + 32 + ar) * K + k0 + ac]);
        __syncthreads();   // previous iteration's readers done
        ushort4 h4, l4;
        h4.x = bf16_rn(a0.x); l4.x = bf16_rn(a0.x - bf16_f32(h4.x));
        h4.y = bf16_rn(a0.y); l4.y = bf16_rn(a0.y - bf16_f32(h4.y));
        h4.z = bf16_rn(a0.z); l4.z = bf16_rn(a0.z - bf16_f32(h4.z));
        h4.w = bf16_rn(a0.w); l4.w = bf16_rn(a0.w - bf16_f32(h4.w));
        *reinterpret_cast<ushort4*>(&Alh[ar][ac]) = h4;
        *reinterpret_cast<ushort4*>(&All[ar][ac]) = l4;
        h4.x = bf16_rn(a1.x); l4.x = bf16_rn(a1.x - bf16_f32(h4.x));
        h4.y = bf16_rn(a1.y); l4.y = bf16_rn(a1.y - bf16_f32(h4.y));
        h4.z = bf16_rn(a1.z); l4.z = bf16_rn(a1.z - bf16_f32(h4.z));
        h4.w = bf16_rn(a1.w); l4.w = bf16_rn(a1.w - bf16_f32(h4.w));
        *reinterpret_cast<ushort4*>(&Alh[ar][ac + 4]) = h4;
        *reinterpret_cast<ushort4*>(&All[ar][ac + 4]) = l4;
        *reinterpret_cast<uint4*>(&Blh[ar][ac]) = bh0;
        *reinterpret_cast<uint4*>(&Bll[ar][ac]) = bl0;
        *reinterpret_cast<uint4*>(&Blh[32 + ar][ac]) = bh1;
        *reinterpret_cast<uint4*>(&Bll[32 + ar][ac]) = bl1;
        __syncthreads();
        #pragma unroll
        for (int ks = 0; ks < 2; ++ks) {
            int kb = ks * 32 + lk * 8;
            bf16x8v ah = *reinterpret_cast<const bf16x8v*>(&Alh[wr * 16 + lr][kb]);
            bf16x8v al = *reinterpret_cast<const bf16x8v*>(&All[wr * 16 + lr][kb]);
            bf16x8v b0h = *reinterpret_cast<const bf16x8v*>(&Blh[wc * 32 + lr][kb]);
            bf16x8v b0l = *reinterpret_cast<const bf16x8v*>(&Bll[wc * 32 + lr][kb]);
            bf16x8v b1h = *reinterpret_cast<const bf16x8v*>(&Blh[wc * 32 + 16 + lr][kb]);
            bf16x8v b1l = *reinterpret_cast<const bf16x8v*>(&Bll[wc * 32 + 16 + lr][kb]);
            acc0 = __builtin_amdgcn_mfma_f32_16x16x32_bf16(ah, b0h, acc0, 0, 0, 0);
            acc0 = __builtin_amdgcn_mfma_f32_16x16x32_bf16(ah, b0l, acc0, 0, 0, 0);
            acc0 = __builtin_amdgcn_mfma_f32_16x16x32_bf16(al, b0h, acc0, 0, 0, 0);
            acc1 = __builtin_amdgcn_mfma_f32_16x16x32_bf16(ah, b1h, acc1, 0, 0, 0);
            acc1 = __builtin_amdgcn_mfma_f32_16x16x32_bf16(ah, b1l, acc1, 0, 0, 0);
            acc1 = __builtin_amdgcn_mfma_f32_16x16x32_bf16(al, b1h, acc1, 0, 0, 0);
        }
    }
    int crow = rowBase + wr * 16 + lk * 4;
    int ccol = colBase + wc * 32 + lr;
    #pragma unroll
    for (int r = 0; r < 4; ++r) {
        C[(size_t)(crow + r) * N + ccol]      = acc0[r];
        C[(size_t)(crow + r) * N + ccol + 16] = acc1[r];
    }
}

// ---------------------------------------------------------------------------
// Kernel 4: per-(n,h) attention dot products  a_src/a_dst  (float4 loads)
// ---------------------------------------------------------------------------
template <int FO>
__global__ __launch_bounds__(256) void adot_kernel(
    const float* __restrict__ Wh, const float* __restrict__ a,
    float* __restrict__ asrc, float* __restrict__ adst) {
    int t = blockIdx.x * blockDim.x + threadIdx.x;
    if (t >= NNODES * NHEADS) return;
    int n = t >> 2, h = t & 3;
    const float4* row = reinterpret_cast<const float4*>(Wh + (size_t)n * (NHEADS * FO) + h * FO);
    const float4* ah  = reinterpret_cast<const float4*>(a + h * 2 * FO);
    float s = 0.f, d = 0.f;
    #pragma unroll
    for (int o = 0; o < FO / 4; ++o) {
        float4 w = row[o];
        float4 u = ah[o];
        float4 v = ah[o + FO / 4];
        s += w.x * u.x + w.y * u.y + w.z * u.z + w.w * u.w;
        d += w.x * v.x + w.y * v.y + w.z * v.z + w.w * v.w;
    }
    asrc[h * NNODES + n] = s;
    adst[h * NNODES + n] = d;
}

// ---------------------------------------------------------------------------
// Kernel 5: sparse softmax + aggregation + ELU. One wave per (n, h).
// float4 gathers: FO/4 lanes per neighbor row -> 4 (FO=64) or 8 (FO=32)
// neighbors per step, unroll 4 -> 16/32 gathers in flight.
// ---------------------------------------------------------------------------
template <int FO>
__global__ __launch_bounds__(256) void agg_kernel(
    const float* __restrict__ Wh,
    const float* __restrict__ asrc, const float* __restrict__ adst,
    const int* __restrict__ nbr, const int* __restrict__ deg,
    float* __restrict__ out) {
    __shared__ float2 sw[4][NBR_STRIDE];
    int wslot = threadIdx.x >> 6;
    int lane = threadIdx.x & 63;
    int wid = blockIdx.x * 4 + wslot;
    int n = wid >> 2, h = wid & 3;
    int dg = deg[n];
    const int* lst = nbr + n * NBR_STRIDE;
    float my_as = asrc[h * NNODES + n];

    int c0 = 0, c1 = 0;
    float e0 = -1e30f, e1 = -1e30f;
    if (lane < dg) {
        c0 = lst[lane];
        float e = my_as + adst[h * NNODES + c0];
        e0 = e >= 0.f ? e : 0.2f * e;
    }
    if (lane + 64 < dg) {
        c1 = lst[lane + 64];
        float e = my_as + adst[h * NNODES + c1];
        e1 = e >= 0.f ? e : 0.2f * e;
    }
    float m = fmaxf(e0, e1);
    #pragma unroll
    for (int s = 32; s; s >>= 1) m = fmaxf(m, __shfl_xor(m, s));
    float p0 = (lane < dg) ? __expf(e0 - m) : 0.f;
    float p1 = (lane + 64 < dg) ? __expf(e1 - m) : 0.f;
    float denom = p0 + p1;
    #pragma unroll
    for (int s = 32; s; s >>= 1) denom += __shfl_xor(denom, s);
    float inv = 1.0f / denom;

    if (lane < dg)      sw[wslot][lane]      = make_float2(p0 * inv, __int_as_float(c0));
    if (lane + 64 < dg) sw[wslot][lane + 64] = make_float2(p1 * inv, __int_as_float(c1));
    __syncthreads();

    constexpr int STRIDE = NHEADS * FO;
    constexpr int LPR = FO / 4;      // lanes per neighbor row (16 or 8)
    constexpr int NPS = 64 / LPR;    // neighbors per step (4 or 8)
    int sub = lane / LPR;
    int dim4 = (lane % LPR) * 4;
    const float* whp = Wh + h * FO + dim4;
    f32x4 acc = {0.f, 0.f, 0.f, 0.f};
    int main_n = (dg / (4 * NPS)) * (4 * NPS);
    int k = 0;
    for (; k < main_n; k += 4 * NPS) {
        #pragma unroll
        for (int u = 0; u < 4; ++u) {
            float2 w = sw[wslot][k + u * NPS + sub];
            int col = __float_as_int(w.y);
            float4 v = *reinterpret_cast<const float4*>(&whp[(size_t)col * STRIDE]);
            acc[0] += w.x * v.x;
            acc[1] += w.x * v.y;
            acc[2] += w.x * v.z;
            acc[3] += w.x * v.w;
        }
    }
    for (; k < dg; k += NPS) {
        if (k + sub < dg) {
            float2 w = sw[wslot][k + sub];
            int col = __float_as_int(w.y);
            float4 v = *reinterpret_cast<const float4*>(&whp[(size_t)col * STRIDE]);
            acc[0] += w.x * v.x;
            acc[1] += w.x * v.y;
            acc[2] += w.x * v.z;
            acc[3] += w.x * v.w;
        }
    }
    #pragma unroll
    for (int s = LPR; s < 64; s <<= 1) {
        acc[0] += __shfl_xor(acc[0], s);
        acc[1] += __shfl_xor(acc[1], s);
        acc[2] += __shfl_xor(acc[2], s);
        acc[3] += __shfl_xor(acc[3], s);
    }
    if (lane < LPR) {
        float4 r;
        r.x = acc[0] > 0.f ? acc[0] : expm1f(acc[0]);
        r.y = acc[1] > 0.f ? acc[1] : expm1f(acc[1]);
        r.z = acc[2] > 0.f ? acc[2] : expm1f(acc[2]);
        r.w = acc[3] > 0.f ? acc[3] : expm1f(acc[3]);
        *reinterpret_cast<float4*>(&out[(size_t)n * STRIDE + h * FO + dim4]) = r;
    }
}

// ---------------------------------------------------------------------------
extern "C" void kernel_launch(void* const* d_in, const int* in_sizes, int n_in,
                              void* d_out, int out_size, void* d_ws, size_t ws_size,
                              hipStream_t stream) {
    const float* x   = (const float*)d_in[0];
    const float* adj = (const float*)d_in[1];
    const float* W1  = (const float*)d_in[2];
    const float* a1  = (const float*)d_in[3];
    const float* W2  = (const float*)d_in[4];
    const float* a2  = (const float*)d_in[5];
    float* out = (float*)d_out;

    char* p = (char*)d_ws;
    auto alloc = [&](size_t bytes) -> void* {
        void* r = (void*)p;
        p += (bytes + 255) & ~(size_t)255;
        return r;
    };
    int*   nbr = (int*)alloc((size_t)NNODES * NBR_STRIDE * 4);
    int*   deg = (int*)alloc((size_t)NNODES * 4);
    unsigned short* B1h = (unsigned short*)alloc((size_t)256 * 512 * 2);
    unsigned short* B1l = (unsigned short*)alloc((size_t)256 * 512 * 2);
    unsigned short* B2h = (unsigned short*)alloc((size_t)128 * 256 * 2);
    unsigned short* B2l = (unsigned short*)alloc((size_t)128 * 256 * 2);
    float* Wh1 = (float*)alloc((size_t)NNODES * 256 * 4);
    float* as1 = (float*)alloc((size_t)NHEADS * NNODES * 4);
    float* ad1 = (float*)alloc((size_t)NHEADS * NNODES * 4);
    float* h1  = (float*)alloc((size_t)NNODES * 256 * 4);
    float* Wh2 = (float*)alloc((size_t)NNODES * 128 * 4);
    float* as2 = (float*)alloc((size_t)NHEADS * NNODES * 4);
    float* ad2 = (float*)alloc((size_t)NHEADS * NNODES * 4);

    // ---- independent prep ----
    pack_b_both_kernel<<<dim3((256 * 512 + 128 * 256) / 256), dim3(256), 0, stream>>>(
        W1, W2, B1h, B1l, B2h, B2l);
    build_nbr_kernel<<<dim3(NNODES / 4), dim3(256), 0, stream>>>(adj, nbr, deg);

    // ---- layer 1 ----
    gemm_split_kernel<512, 256><<<dim3(NNODES / 32, 256 / 64), dim3(256), 0, stream>>>(
        x, B1h, B1l, Wh1);
    adot_kernel<64><<<dim3(NNODES * NHEADS / 256), dim3(256), 0, stream>>>(
        Wh1, a1, as1, ad1);
    agg_kernel<64><<<dim3(NNODES * NHEADS / 4), dim3(256), 0, stream>>>(
        Wh1, as1, ad1, nbr, deg, h1);

    // ---- layer 2 ----
    gemm_split_kernel<256, 128><<<dim3(NNODES / 32, 128 / 64), dim3(256), 0, stream>>>(
        h1, B2h, B2l, Wh2);
    adot_kernel<32><<<dim3(NNODES * NHEADS / 256), dim3(256), 0, stream>>>(
        Wh2, a2, as2, ad2);
    agg_kernel<32><<<dim3(NNODES * NHEADS / 4), dim3(256), 0, stream>>>(
        Wh2, as2, ad2, nbr, deg, out);
}